// Round 7
// baseline (350.857 us; speedup 1.0000x reference)
//
#include <hip/hip_runtime.h>

// Problem constants
#define NT 524288          // tokens
#define NE 64              // experts
#define NK 8               // top-k
#define TPB 128            // tokens per block
#define NBLK (NT / TPB)    // 4096 blocks
#define SPB (TPB * NK)     // 1024 slots per block
#define NSUP (NBLK / 64)   // 64 supers of 64 blocks

// ---------------------------------------------------------------------------
// K1: R4's proven lightweight topk kernel (softmax + top-8 + passthrough +
// per-block expert counts), plus ONE atomicAdd per (block,expert) into the
// 2-level superCnt table. No ids/rnk LDS, no packed stores, no prefix loop —
// R6 showed those push the allocator into a 32-VGPR spill corner (+15 MB
// scratch, 164us). blockCounts stays transposed [expert][block].
// ---------------------------------------------------------------------------
__global__ __launch_bounds__(256) void topk_kernel(
    const float* __restrict__ logits,
    float* __restrict__ out_scores,
    float* __restrict__ out_assign,
    float* __restrict__ out_logits,
    int* __restrict__ blockCounts,      // ws: [NE][NBLK]
    int* __restrict__ superCnt)         // ws: [NE][NSUP], pre-zeroed
{
    __shared__ int wcnt[4][NE];          // 1 KB

    const int t = threadIdx.x;
    const int b = blockIdx.x;
    const int g = t & 7;                 // lane within 8-lane token group
    const int tok_in_pass = t >> 3;      // 0..31
    const int w = t >> 6;                // wave 0..3
    const int l = t & 63;                // lane
    const unsigned long long lt_mask = (l == 0) ? 0ull : ((~0ull) >> (64 - l));

    wcnt[w][l] = 0;
    __syncthreads();                     // barrier 1

    #pragma unroll
    for (int pass = 0; pass < 4; ++pass) {
        const int token = b * TPB + pass * 32 + tok_in_pass;
        const float* lp = logits + (size_t)token * NE + g * 8;
        float4 v0 = *(const float4*)lp;
        float4 v1 = *(const float4*)(lp + 4);
        float* op = out_logits + (size_t)token * NE + g * 8;
        *(float4*)op = v0;
        *(float4*)(op + 4) = v1;

        float lv[8] = {v0.x, v0.y, v0.z, v0.w, v1.x, v1.y, v1.z, v1.w};

        // softmax: max over 64 (local 8 + 3-step shuffle within group of 8)
        float m = lv[0];
        #pragma unroll
        for (int j = 1; j < 8; ++j) m = fmaxf(m, lv[j]);
        #pragma unroll
        for (int sh = 1; sh < 8; sh <<= 1) m = fmaxf(m, __shfl_xor(m, sh, 64));

        float p[8];
        float s = 0.f;
        #pragma unroll
        for (int j = 0; j < 8; ++j) { p[j] = expf(lv[j] - m); s += p[j]; }
        #pragma unroll
        for (int sh = 1; sh < 8; sh <<= 1) s += __shfl_xor(s, sh, 64);
        const float rs = 1.0f / s;       // 1 div + 8 muls, <=1 ulp vs p/s
        #pragma unroll
        for (int j = 0; j < 8; ++j) p[j] = p[j] * rs;

        // iterative top-8 on probs; tie -> smaller global index
        float sc = 0.f; int id = 0;
        #pragma unroll
        for (int k = 0; k < NK; ++k) {
            float bv = p[0]; int bi = 0;
            #pragma unroll
            for (int j = 1; j < 8; ++j)
                if (p[j] > bv) { bv = p[j]; bi = j; }   // strict > keeps low idx
            int bidx = g * 8 + bi;
            #pragma unroll
            for (int sh = 1; sh < 8; sh <<= 1) {
                float ov = __shfl_xor(bv, sh, 64);
                int   oi = __shfl_xor(bidx, sh, 64);
                if (ov > bv || (ov == bv && oi < bidx)) { bv = ov; bidx = oi; }
            }
            if (g == k) { sc = bv; id = bidx; }
            if ((bidx >> 3) == g) p[bidx & 7] = -1.0f;  // kill winner
        }

        const size_t slot = (size_t)token * NK + g;     // coalesced
        out_scores[slot] = sc;
        out_assign[slot] = (float)id;

        // histogram: ballot-match, leader accumulates its group's count
        unsigned long long mask = ~0ull;
        #pragma unroll
        for (int bit = 0; bit < 6; ++bit) {
            unsigned long long bb = __ballot((id >> bit) & 1);
            mask &= ((id >> bit) & 1) ? bb : ~bb;
        }
        if ((mask & lt_mask) == 0ull)
            atomicAdd(&wcnt[w][id], __popcll(mask));    // leader only
    }

    __syncthreads();                     // barrier 2
    if (t < NE) {
        const int c = wcnt[0][t] + wcnt[1][t] + wcnt[2][t] + wcnt[3][t];
        blockCounts[t * NBLK + b] = c;                  // transposed
        atomicAdd(&superCnt[t * NSUP + (b >> 6)], c);   // 2-level table
    }
}

// ---------------------------------------------------------------------------
// finalize: the ONLY other kernel. Replaces scan_kernel + offs_kernel.
// Block b rebuilds its global per-expert base from the 2-level tables
// (<=63 super entries + <=63 in-super block entries, L2-hot; math verified
// end-to-end in round 6), then recomputes stable in-block ranks from
// out_assign via the R4-verified ballot path and writes final offsets.
// Block 0 also emits out_counts from the superCnt row sums.
// ---------------------------------------------------------------------------
__global__ __launch_bounds__(256) void finalize_kernel(
    const int* __restrict__ blockCounts,   // [NE][NBLK] per-block totals
    const int* __restrict__ superCnt,      // [NE][NSUP] per-super totals
    const float* __restrict__ out_assign,
    float* __restrict__ out_counts,
    float* __restrict__ out_offs)
{
    __shared__ int cnt[4][4][NE];        // [tile][wave][expert], 4 KB
    __shared__ int base[NE];
    const int t = threadIdx.x;
    const int b = blockIdx.x;
    const int w = t >> 6;                // wave 0..3
    const int l = t & 63;                // lane
    const unsigned long long lt_mask = (l == 0) ? 0ull : ((~0ull) >> (64 - l));

    #pragma unroll
    for (int tau = 0; tau < 4; ++tau) cnt[tau][w][l] = 0;

    if (t < NE) {
        const int s = b >> 6;
        const int b0 = s << 6;
        int acc = 0;
        for (int sp = 0; sp < s; ++sp) acc += superCnt[t * NSUP + sp];
        for (int bp = b0; bp < b; ++bp) acc += blockCounts[t * NBLK + bp];
        base[t] = acc;
    }
    if (b == 0 && t < NE) {
        int tot = 0;
        #pragma unroll
        for (int sp = 0; sp < NSUP; ++sp) tot += superCnt[t * NSUP + sp];
        out_counts[t] = (float)tot;
    }
    __syncthreads();                     // barrier 1

    int e_r[4];
    unsigned long long mask_r[4];
    #pragma unroll
    for (int tau = 0; tau < 4; ++tau) {
        const int gslot = b * SPB + tau * 256 + t;     // token-major order
        const int e = (int)out_assign[gslot];
        e_r[tau] = e;
        unsigned long long mask = ~0ull;
        #pragma unroll
        for (int bit = 0; bit < 6; ++bit) {
            unsigned long long bb = __ballot((e >> bit) & 1);
            mask &= ((e >> bit) & 1) ? bb : ~bb;
        }
        mask_r[tau] = mask;
        if ((mask & lt_mask) == 0ull)
            atomicAdd(&cnt[tau][w][e], __popcll(mask));  // leader only
    }
    __syncthreads();                     // barrier 2

    #pragma unroll
    for (int tau = 0; tau < 4; ++tau) {
        const int e = e_r[tau];
        int before = base[e];
        #pragma unroll
        for (int tau2 = 0; tau2 < 4; ++tau2)
            if (tau2 < tau)
                before += cnt[tau2][0][e] + cnt[tau2][1][e]
                        + cnt[tau2][2][e] + cnt[tau2][3][e];
        if (w > 0) before += cnt[tau][0][e];
        if (w > 1) before += cnt[tau][1][e];
        if (w > 2) before += cnt[tau][2][e];
        const int gslot = b * SPB + tau * 256 + t;
        out_offs[gslot] = (float)(before + __popcll(mask_r[tau] & lt_mask));
    }
}

extern "C" void kernel_launch(void* const* d_in, const int* in_sizes, int n_in,
                              void* d_out, int out_size, void* d_ws, size_t ws_size,
                              hipStream_t stream) {
    // inputs: [0] expert_counts placeholder, [1] assignments placeholder,
    //         [2] offsets placeholder, [3] logits [NT, NE] float32
    const float* logits = (const float*)d_in[3];

    float* out = (float*)d_out;
    float* out_counts = out;                                   // [64]
    float* out_scores = out + NE;                              // [NT*NK]
    float* out_assign = out_scores + (size_t)NT * NK;          // [NT*NK]
    float* out_offs   = out_assign + (size_t)NT * NK;          // [NT*NK]
    float* out_logits = out_offs + (size_t)NT * NK;            // [NT*NE]

    int* blockCounts = (int*)d_ws;                             // 1 MB
    int* superCnt    = blockCounts + (size_t)NE * NBLK;        // 16 KB

    // zero the 16 KB super table (graph memset node, feeds only K1)
    hipMemsetAsync(superCnt, 0, (size_t)NE * NSUP * 4, stream);
    hipLaunchKernelGGL(topk_kernel, dim3(NBLK), dim3(256), 0, stream,
                       logits, out_scores, out_assign, out_logits,
                       blockCounts, superCnt);
    hipLaunchKernelGGL(finalize_kernel, dim3(NBLK), dim3(256), 0, stream,
                       blockCounts, superCnt, out_assign, out_counts, out_offs);
}

// Round 8
// 338.024 us; speedup vs baseline: 1.0380x; 1.0380x over previous
//
#include <hip/hip_runtime.h>

// Problem constants
#define NT 524288          // tokens
#define NE 64              // experts
#define NK 8               // top-k
#define TPB 128            // tokens per block
#define NBLK (NT / TPB)    // 4096 blocks
#define SPB (TPB * NK)     // 1024 slots per block
#define NSUP (NBLK / 64)   // 64 supers of 64 blocks

// ---------------------------------------------------------------------------
// K1: R4's proven lightweight topk kernel (softmax + top-8 + passthrough +
// per-block expert counts). Only change vs R4: expert-minor layouts —
// blockCounts[b][e] (coalesced 64-int row write) and one atomicAdd into
// superCnt[b>>6][e] (64 consecutive atomics). No ids/rnk LDS, no packed
// stores, no prefix loop (R6's 32-VGPR spill lesson).
// ---------------------------------------------------------------------------
__global__ __launch_bounds__(256) void topk_kernel(
    const float* __restrict__ logits,
    float* __restrict__ out_scores,
    float* __restrict__ out_assign,
    float* __restrict__ out_logits,
    int* __restrict__ blockCounts,      // ws: [NBLK][NE]
    int* __restrict__ superCnt)         // ws: [NSUP][NE], pre-zeroed
{
    __shared__ int wcnt[4][NE];          // 1 KB

    const int t = threadIdx.x;
    const int b = blockIdx.x;
    const int g = t & 7;                 // lane within 8-lane token group
    const int tok_in_pass = t >> 3;      // 0..31
    const int w = t >> 6;                // wave 0..3
    const int l = t & 63;                // lane
    const unsigned long long lt_mask = (l == 0) ? 0ull : ((~0ull) >> (64 - l));

    wcnt[w][l] = 0;
    __syncthreads();                     // barrier 1

    #pragma unroll
    for (int pass = 0; pass < 4; ++pass) {
        const int token = b * TPB + pass * 32 + tok_in_pass;
        const float* lp = logits + (size_t)token * NE + g * 8;
        float4 v0 = *(const float4*)lp;
        float4 v1 = *(const float4*)(lp + 4);
        float* op = out_logits + (size_t)token * NE + g * 8;
        *(float4*)op = v0;
        *(float4*)(op + 4) = v1;

        float lv[8] = {v0.x, v0.y, v0.z, v0.w, v1.x, v1.y, v1.z, v1.w};

        // softmax: max over 64 (local 8 + 3-step shuffle within group of 8)
        float m = lv[0];
        #pragma unroll
        for (int j = 1; j < 8; ++j) m = fmaxf(m, lv[j]);
        #pragma unroll
        for (int sh = 1; sh < 8; sh <<= 1) m = fmaxf(m, __shfl_xor(m, sh, 64));

        float p[8];
        float s = 0.f;
        #pragma unroll
        for (int j = 0; j < 8; ++j) { p[j] = expf(lv[j] - m); s += p[j]; }
        #pragma unroll
        for (int sh = 1; sh < 8; sh <<= 1) s += __shfl_xor(s, sh, 64);
        const float rs = 1.0f / s;       // 1 div + 8 muls, <=1 ulp vs p/s
        #pragma unroll
        for (int j = 0; j < 8; ++j) p[j] = p[j] * rs;

        // iterative top-8 on probs; tie -> smaller global index
        float sc = 0.f; int id = 0;
        #pragma unroll
        for (int k = 0; k < NK; ++k) {
            float bv = p[0]; int bi = 0;
            #pragma unroll
            for (int j = 1; j < 8; ++j)
                if (p[j] > bv) { bv = p[j]; bi = j; }   // strict > keeps low idx
            int bidx = g * 8 + bi;
            #pragma unroll
            for (int sh = 1; sh < 8; sh <<= 1) {
                float ov = __shfl_xor(bv, sh, 64);
                int   oi = __shfl_xor(bidx, sh, 64);
                if (ov > bv || (ov == bv && oi < bidx)) { bv = ov; bidx = oi; }
            }
            if (g == k) { sc = bv; id = bidx; }
            if ((bidx >> 3) == g) p[bidx & 7] = -1.0f;  // kill winner
        }

        const size_t slot = (size_t)token * NK + g;     // coalesced
        out_scores[slot] = sc;
        out_assign[slot] = (float)id;

        // histogram: ballot-match, leader accumulates its group's count
        unsigned long long mask = ~0ull;
        #pragma unroll
        for (int bit = 0; bit < 6; ++bit) {
            unsigned long long bb = __ballot((id >> bit) & 1);
            mask &= ((id >> bit) & 1) ? bb : ~bb;
        }
        if ((mask & lt_mask) == 0ull)
            atomicAdd(&wcnt[w][id], __popcll(mask));    // leader only
    }

    __syncthreads();                     // barrier 2
    if (t < NE) {
        const int c = wcnt[0][t] + wcnt[1][t] + wcnt[2][t] + wcnt[3][t];
        blockCounts[b * NE + t] = c;                    // expert-minor, coalesced
        atomicAdd(&superCnt[(b >> 6) * NE + t], c);     // 2-level table
    }
}

// ---------------------------------------------------------------------------
// finalize: the only exposed kernel. Base reconstruction is PARALLEL and
// COALESCED (R7 lesson: the serial stride-16KB version cost +23us): 4 threads
// per expert (e = t&63, q = t>>6), each sums <=16 super entries + <=16
// in-super block entries; every load iteration reads 256 contiguous bytes
// (expert-minor layout), all L2-hot. LDS-combine -> base[e]. Then the
// R4-verified ballot rank path and the final offset write. Block 0 emits
// out_counts.
// ---------------------------------------------------------------------------
__global__ __launch_bounds__(256) void finalize_kernel(
    const int* __restrict__ blockCounts,   // [NBLK][NE]
    const int* __restrict__ superCnt,      // [NSUP][NE]
    const float* __restrict__ out_assign,
    float* __restrict__ out_counts,
    float* __restrict__ out_offs)
{
    __shared__ int cnt[4][4][NE];        // [tile][wave][expert], 4 KB
    __shared__ int part[4][NE];          // base partials, 1 KB
    __shared__ int base[NE];
    const int t = threadIdx.x;
    const int b = blockIdx.x;
    const int w = t >> 6;                // wave 0..3
    const int l = t & 63;                // lane
    const unsigned long long lt_mask = (l == 0) ? 0ull : ((~0ull) >> (64 - l));

    #pragma unroll
    for (int tau = 0; tau < 4; ++tau) cnt[tau][w][l] = 0;

    // coalesced 2-level base reconstruction
    {
        const int e = t & 63;
        const int q = t >> 6;            // 0..3: quarter of the range
        const int s = b >> 6;            // super index
        const int b0 = s << 6;           // first block of this super
        int acc = 0;
        const int sp_hi = min(q * 16 + 16, s);
        for (int sp = q * 16; sp < sp_hi; ++sp)
            acc += superCnt[sp * NE + e];               // 256B contiguous
        const int bp_hi = min(b0 + q * 16 + 16, b);
        for (int bp = b0 + q * 16; bp < bp_hi; ++bp)
            acc += blockCounts[bp * NE + e];            // 256B contiguous
        part[q][e] = acc;
    }
    __syncthreads();                     // barrier 1
    if (t < NE) base[t] = part[0][t] + part[1][t] + part[2][t] + part[3][t];
    if (b == 0 && t < NE) {
        int tot = 0;
        #pragma unroll
        for (int sp = 0; sp < NSUP; ++sp) tot += superCnt[sp * NE + t];
        out_counts[t] = (float)tot;
    }
    __syncthreads();                     // barrier 2 (base visible)

    int e_r[4];
    unsigned long long mask_r[4];
    #pragma unroll
    for (int tau = 0; tau < 4; ++tau) {
        const int gslot = b * SPB + tau * 256 + t;     // token-major order
        const int e = (int)out_assign[gslot];
        e_r[tau] = e;
        unsigned long long mask = ~0ull;
        #pragma unroll
        for (int bit = 0; bit < 6; ++bit) {
            unsigned long long bb = __ballot((e >> bit) & 1);
            mask &= ((e >> bit) & 1) ? bb : ~bb;
        }
        mask_r[tau] = mask;
        if ((mask & lt_mask) == 0ull)
            atomicAdd(&cnt[tau][w][e], __popcll(mask));  // leader only
    }
    __syncthreads();                     // barrier 3

    #pragma unroll
    for (int tau = 0; tau < 4; ++tau) {
        const int e = e_r[tau];
        int before = base[e];
        #pragma unroll
        for (int tau2 = 0; tau2 < 4; ++tau2)
            if (tau2 < tau)
                before += cnt[tau2][0][e] + cnt[tau2][1][e]
                        + cnt[tau2][2][e] + cnt[tau2][3][e];
        if (w > 0) before += cnt[tau][0][e];
        if (w > 1) before += cnt[tau][1][e];
        if (w > 2) before += cnt[tau][2][e];
        const int gslot = b * SPB + tau * 256 + t;
        out_offs[gslot] = (float)(before + __popcll(mask_r[tau] & lt_mask));
    }
}

extern "C" void kernel_launch(void* const* d_in, const int* in_sizes, int n_in,
                              void* d_out, int out_size, void* d_ws, size_t ws_size,
                              hipStream_t stream) {
    // inputs: [0] expert_counts placeholder, [1] assignments placeholder,
    //         [2] offsets placeholder, [3] logits [NT, NE] float32
    const float* logits = (const float*)d_in[3];

    float* out = (float*)d_out;
    float* out_counts = out;                                   // [64]
    float* out_scores = out + NE;                              // [NT*NK]
    float* out_assign = out_scores + (size_t)NT * NK;          // [NT*NK]
    float* out_offs   = out_assign + (size_t)NT * NK;          // [NT*NK]
    float* out_logits = out_offs + (size_t)NT * NK;            // [NT*NE]

    int* blockCounts = (int*)d_ws;                             // [NBLK][NE] 1 MB
    int* superCnt    = blockCounts + (size_t)NBLK * NE;        // [NSUP][NE] 16 KB

    // zero the 16 KB super table (graph memset node, feeds only K1)
    hipMemsetAsync(superCnt, 0, (size_t)NSUP * NE * 4, stream);
    hipLaunchKernelGGL(topk_kernel, dim3(NBLK), dim3(256), 0, stream,
                       logits, out_scores, out_assign, out_logits,
                       blockCounts, superCnt);
    hipLaunchKernelGGL(finalize_kernel, dim3(NBLK), dim3(256), 0, stream,
                       blockCounts, superCnt, out_assign, out_counts, out_offs);
}

// Round 9
// 327.939 us; speedup vs baseline: 1.0699x; 1.0308x over previous
//
#include <hip/hip_runtime.h>

// Problem constants
#define NT 524288          // tokens
#define NE 64              // experts
#define NK 8               // top-k
#define TPB 128            // tokens per block
#define NBLK (NT / TPB)    // 4096 blocks
#define SPB (TPB * NK)     // 1024 slots per block

// ---------------------------------------------------------------------------
// BEST-MEASURED CONFIGURATION (round 4: 328.05 us). Restored verbatim after
// rounds 5-8 proved every structural alternative worse:
//  - cooperative fusion (R5): no overlap with harness fills, +188 us
//  - rank bookkeeping in K1 (R6): 32-VGPR spill corner, K1 164 us
//  - scan folded into finalize (R7 serial / R8 coalesced): repeats the
//    prefix reconstruction 4096x instead of once, +10..23 us
// Chain: K1 (hidden under fills) -> scan (once, 64 blocks) -> offs (simple
// base load + ballot ranks). K1 duration is off the critical path below
// ~150 us (R3: K1=152 -> total unchanged), so no further K1 tuning pays.
// ---------------------------------------------------------------------------

// Kernel 1: softmax + top-8 + logits passthrough + per-block expert counts.
// TWO barriers total; 4 barrier-free passes. NO min-waves launch bound: the
// hot shuffles are all mask 1/2/4 (DPP, low latency) so this kernel wants
// VGPRs/ILP, not occupancy (R3 lesson: (256,4) bound caused a spill-fest).
// blockCounts layout TRANSPOSED: [expert][block] so K2 is coalesced.
__global__ __launch_bounds__(256) void topk_kernel(
    const float* __restrict__ logits,
    float* __restrict__ out_scores,
    float* __restrict__ out_assign,
    float* __restrict__ out_logits,
    int* __restrict__ blockCounts)      // ws: [NE][NBLK]
{
    __shared__ int wcnt[4][NE];          // 1 KB, per-wave histogram rows

    const int t = threadIdx.x;
    const int b = blockIdx.x;
    const int g = t & 7;                 // lane within 8-lane token group
    const int tok_in_pass = t >> 3;      // 0..31
    const int w = t >> 6;                // wave 0..3
    const int l = t & 63;                // lane
    const unsigned long long lt_mask = (l == 0) ? 0ull : ((~0ull) >> (64 - l));

    wcnt[w][l] = 0;                      // covers all 4x64 entries
    __syncthreads();                     // barrier 1

    #pragma unroll
    for (int pass = 0; pass < 4; ++pass) {
        const int ltok = pass * 32 + tok_in_pass;       // 0..127
        const int token = b * TPB + ltok;
        const float* lp = logits + (size_t)token * NE + g * 8;
        float4 v0 = *(const float4*)lp;
        float4 v1 = *(const float4*)(lp + 4);
        // passthrough copy
        float* op = out_logits + (size_t)token * NE + g * 8;
        *(float4*)op = v0;
        *(float4*)(op + 4) = v1;

        float lv[8] = {v0.x, v0.y, v0.z, v0.w, v1.x, v1.y, v1.z, v1.w};

        // softmax: max over 64 (local 8 + 3-step shuffle within group of 8)
        float m = lv[0];
        #pragma unroll
        for (int j = 1; j < 8; ++j) m = fmaxf(m, lv[j]);
        #pragma unroll
        for (int sh = 1; sh < 8; sh <<= 1) m = fmaxf(m, __shfl_xor(m, sh, 64));

        float p[8];
        float s = 0.f;
        #pragma unroll
        for (int j = 0; j < 8; ++j) { p[j] = expf(lv[j] - m); s += p[j]; }
        #pragma unroll
        for (int sh = 1; sh < 8; sh <<= 1) s += __shfl_xor(s, sh, 64);
        // one IEEE div + 8 muls instead of 8 divs: <=1 ulp vs p[j]/s,
        // three orders of magnitude under the >=2^-10 harness tolerance.
        const float rs = 1.0f / s;
        #pragma unroll
        for (int j = 0; j < 8; ++j) p[j] = p[j] * rs;

        // iterative top-8 on probs; tie -> smaller global index
        float sc = 0.f; int id = 0;
        #pragma unroll
        for (int k = 0; k < NK; ++k) {
            float bv = p[0]; int bi = 0;
            #pragma unroll
            for (int j = 1; j < 8; ++j)
                if (p[j] > bv) { bv = p[j]; bi = j; }   // strict > keeps low idx
            int bidx = g * 8 + bi;
            #pragma unroll
            for (int sh = 1; sh < 8; sh <<= 1) {
                float ov = __shfl_xor(bv, sh, 64);
                int   oi = __shfl_xor(bidx, sh, 64);
                if (ov > bv || (ov == bv && oi < bidx)) { bv = ov; bidx = oi; }
            }
            if (g == k) { sc = bv; id = bidx; }
            if ((bidx >> 3) == g) p[bidx & 7] = -1.0f;  // kill winner
        }

        const size_t slot = (size_t)token * NK + g;     // coalesced
        out_scores[slot] = sc;
        out_assign[slot] = (float)id;

        // histogram: ballot-match, leader accumulates its group's count
        const int e = id;
        unsigned long long mask = ~0ull;
        #pragma unroll
        for (int bit = 0; bit < 6; ++bit) {
            unsigned long long bb = __ballot((e >> bit) & 1);
            mask &= ((e >> bit) & 1) ? bb : ~bb;
        }
        if ((mask & lt_mask) == 0ull)
            atomicAdd(&wcnt[w][e], __popcll(mask));     // leader only
    }

    __syncthreads();                     // barrier 2
    if (t < NE) {
        const int c = wcnt[0][t] + wcnt[1][t] + wcnt[2][t] + wcnt[3][t];
        blockCounts[t * NBLK + b] = c;   // transposed layout
    }
}

// ---------------------------------------------------------------------------
// Kernel 2: per-expert exclusive prefix sum over 4096 block counts
// (in place -> block starts). One block per expert; transposed layout makes
// every global access fully coalesced. LDS staging padded (j + j/16) to
// avoid 16-int-stride bank conflicts. Totals -> counts output.
// ---------------------------------------------------------------------------
__global__ __launch_bounds__(256) void scan_kernel(
    int* __restrict__ blockCounts, float* __restrict__ out_counts)
{
    __shared__ int buf[NBLK + (NBLK >> 4)];   // 4352 ints = 17 KB
    __shared__ int part[256];
    const int e = blockIdx.x;            // 0..63
    const int t = threadIdx.x;           // 0..255
    int* col = blockCounts + (size_t)e * NBLK;

    #pragma unroll
    for (int i = 0; i < 16; ++i) {
        const int j = i * 256 + t;       // coalesced global read
        buf[j + (j >> 4)] = col[j];
    }
    __syncthreads();

    int loc[16];
    int s = 0;
    #pragma unroll
    for (int i = 0; i < 16; ++i) {       // thread t owns blocks [16t, 16t+16)
        const int j = t * 16 + i;
        loc[i] = s;
        s += buf[j + (j >> 4)];
    }
    part[t] = s;
    __syncthreads();

    // Hillis-Steele inclusive scan over 256 partials
    for (int off = 1; off < 256; off <<= 1) {
        int v = (t >= off) ? part[t - off] : 0;
        __syncthreads();
        part[t] += v;
        __syncthreads();
    }
    const int run = (t == 0) ? 0 : part[t - 1];

    #pragma unroll
    for (int i = 0; i < 16; ++i) {
        const int j = t * 16 + i;
        buf[j + (j >> 4)] = run + loc[i];    // exclusive start per block
    }
    __syncthreads();
    #pragma unroll
    for (int i = 0; i < 16; ++i) {
        const int j = i * 256 + t;
        col[j] = buf[j + (j >> 4)];      // coalesced global write
    }
    if (t == 255) out_counts[e] = (float)part[255];
}

// ---------------------------------------------------------------------------
// Kernel 3: recompute stable in-block ranks from out_assign and write final
// offsets. TWO barriers. All 4 tiles loaded first (masks kept in registers),
// leaders atomic-accumulate cnt[tile][wave][e], one barrier, then all ranks
// computed as LDS prefix sums and streamed out.
// ---------------------------------------------------------------------------
__global__ __launch_bounds__(256) void offs_kernel(
    const int* __restrict__ blockCounts,   // [NE][NBLK] scanned starts
    const float* __restrict__ out_assign,
    float* __restrict__ out_offs)
{
    __shared__ int cnt[4][4][NE];        // [tile][wave][expert], 4 KB
    __shared__ int base[NE];
    const int t = threadIdx.x;
    const int b = blockIdx.x;
    const int w = t >> 6;                // wave 0..3
    const int l = t & 63;                // lane
    const unsigned long long lt_mask = (l == 0) ? 0ull : ((~0ull) >> (64 - l));

    #pragma unroll
    for (int tau = 0; tau < 4; ++tau) cnt[tau][w][l] = 0;
    if (t < NE) base[t] = blockCounts[t * NBLK + b];
    __syncthreads();                     // barrier 1

    int e_r[4];
    unsigned long long mask_r[4];
    #pragma unroll
    for (int tau = 0; tau < 4; ++tau) {
        const int gslot = b * SPB + tau * 256 + t;     // token-major order
        const int e = (int)out_assign[gslot];
        e_r[tau] = e;
        unsigned long long mask = ~0ull;
        #pragma unroll
        for (int bit = 0; bit < 6; ++bit) {
            unsigned long long bb = __ballot((e >> bit) & 1);
            mask &= ((e >> bit) & 1) ? bb : ~bb;
        }
        mask_r[tau] = mask;
        if ((mask & lt_mask) == 0ull)
            atomicAdd(&cnt[tau][w][e], __popcll(mask));  // leader only
    }
    __syncthreads();                     // barrier 2

    #pragma unroll
    for (int tau = 0; tau < 4; ++tau) {
        const int e = e_r[tau];
        int before = base[e];
        #pragma unroll
        for (int tau2 = 0; tau2 < 4; ++tau2)
            if (tau2 < tau)
                before += cnt[tau2][0][e] + cnt[tau2][1][e]
                        + cnt[tau2][2][e] + cnt[tau2][3][e];
        if (w > 0) before += cnt[tau][0][e];
        if (w > 1) before += cnt[tau][1][e];
        if (w > 2) before += cnt[tau][2][e];
        const int gslot = b * SPB + tau * 256 + t;
        out_offs[gslot] = (float)(before + __popcll(mask_r[tau] & lt_mask));
    }
}

extern "C" void kernel_launch(void* const* d_in, const int* in_sizes, int n_in,
                              void* d_out, int out_size, void* d_ws, size_t ws_size,
                              hipStream_t stream) {
    // inputs: [0] expert_counts placeholder, [1] assignments placeholder,
    //         [2] offsets placeholder, [3] logits [NT, NE] float32
    const float* logits = (const float*)d_in[3];

    float* out = (float*)d_out;
    float* out_counts = out;                                   // [64]
    float* out_scores = out + NE;                              // [NT*NK]
    float* out_assign = out_scores + (size_t)NT * NK;          // [NT*NK]
    float* out_offs   = out_assign + (size_t)NT * NK;          // [NT*NK]
    float* out_logits = out_offs + (size_t)NT * NK;            // [NT*NE]

    int* blockCounts = (int*)d_ws;                             // 64*4096*4 = 1 MB

    hipLaunchKernelGGL(topk_kernel, dim3(NBLK), dim3(256), 0, stream,
                       logits, out_scores, out_assign, out_logits, blockCounts);
    hipLaunchKernelGGL(scan_kernel, dim3(NE), dim3(256), 0, stream,
                       blockCounts, out_counts);
    hipLaunchKernelGGL(offs_kernel, dim3(NBLK), dim3(256), 0, stream,
                       blockCounts, out_assign, out_offs);
}